// Round 14
// baseline (626.494 us; speedup 1.0000x reference)
//
#include <hip/hip_runtime.h>
#include <hip/hip_bf16.h>
#include <cstdint>
#include <cstddef>

#define NN   100000
#define NE   1600000
#define HID  256
#define OUTC 40

typedef __attribute__((ext_vector_type(8))) short bf16x8;
typedef __attribute__((ext_vector_type(4))) float f32x4;

static __device__ __forceinline__ ushort f2bf(float f) {
    __hip_bfloat16 h = __float2bfloat16(f);
    return *reinterpret_cast<ushort*>(&h);
}
static __device__ __forceinline__ float bflo(unsigned u) { return __uint_as_float(u << 16); }
static __device__ __forceinline__ float bfhi(unsigned u) { return __uint_as_float(u & 0xffff0000u); }
// unsigned byte k of word w -> float (selects to v_cvt_f32_ubyteN)
static __device__ __forceinline__ float ubf(unsigned w, int k) {
    return (float)((w >> (8 * k)) & 255u);
}

// ---------------- CSR build ----------------
__global__ void k_count(const int* __restrict__ dst, int* __restrict__ cnt) {
    int i = blockIdx.x * blockDim.x + threadIdx.x;
    if (i < NE) atomicAdd(&cnt[dst[i]], 1);
}

__global__ void k_blocksum(const int* __restrict__ cnt, int* __restrict__ bsum) {
    __shared__ int s[256];
    int t = threadIdx.x;
    int n = blockIdx.x * 256 + t;
    s[t] = (n < NN) ? cnt[n] : 0;
    __syncthreads();
    for (int off = 128; off; off >>= 1) {
        if (t < off) s[t] += s[t + off];
        __syncthreads();
    }
    if (t == 0) bsum[blockIdx.x] = s[0];
}

__global__ void k_scanblock(const int* __restrict__ bsum, int* __restrict__ boff, int nb) {
    __shared__ int s[512];
    int t = threadIdx.x;
    int v = (t < nb) ? bsum[t] : 0;
    s[t] = v;
    __syncthreads();
    for (int off = 1; off < 512; off <<= 1) {
        int u = (t >= off) ? s[t - off] : 0;
        __syncthreads();
        s[t] += u;
        __syncthreads();
    }
    if (t < nb) boff[t] = s[t] - v;
}

__global__ void k_rowptr(const int* __restrict__ cnt, const int* __restrict__ boff,
                         int* __restrict__ rowptr, int* __restrict__ fillp,
                         float* __restrict__ invd) {
    __shared__ int s[256];
    int t = threadIdx.x;
    int n = blockIdx.x * 256 + t;
    int c = (n < NN) ? cnt[n] : 0;
    s[t] = c;
    __syncthreads();
    for (int off = 1; off < 256; off <<= 1) {
        int u = (t >= off) ? s[t - off] : 0;
        __syncthreads();
        s[t] += u;
        __syncthreads();
    }
    if (n < NN) {
        int excl = boff[blockIdx.x] + s[t] - c;
        rowptr[n] = excl;
        fillp[n]  = excl;
        invd[n]   = 1.0f / (float)(c > 1 ? c : 1);
    }
    if (n == 0) rowptr[NN] = NE;
}

__global__ void k_fill(const int* __restrict__ src, const int* __restrict__ dst,
                       int* __restrict__ fillp, int* __restrict__ colidx) {
    int i = blockIdx.x * blockDim.x + threadIdx.x;
    if (i < NE) {
        int p = atomicAdd(&fillp[dst[i]], 1);
        colidx[p] = src[i];
    }
}

// ---------------- weights fp32 [OC][D] -> fragment-major bf16 ----------------
__global__ void k_cvtfrag(const float* __restrict__ W, ushort* __restrict__ dst,
                          int ocreal, int d, int nf) {
    int f = blockIdx.x * 256 + threadIdx.x;
    if (f >= nf) return;
    int lm = f & 15, lk = (f >> 4) & 3;
    int rest = f >> 6;
    int dk = d / 32;
    int kk = rest % dk, cc = rest / dk;
    int row = cc * 16 + lm, col = kk * 32 + lk * 8;
    unsigned q0 = 0, q1 = 0, q2 = 0, q3 = 0;
    if (row < ocreal) {
        const float4* p = (const float4*)(W + (size_t)row * d + col);
        float4 a = p[0], b = p[1];
        q0 = (unsigned)f2bf(a.x) | ((unsigned)f2bf(a.y) << 16);
        q1 = (unsigned)f2bf(a.z) | ((unsigned)f2bf(a.w) << 16);
        q2 = (unsigned)f2bf(b.x) | ((unsigned)f2bf(b.y) << 16);
        q3 = (unsigned)f2bf(b.z) | ((unsigned)f2bf(b.w) << 16);
    }
    *(uint4*)(dst + (size_t)f * 8) = make_uint4(q0, q1, q2, q3);
}

// ---------------- x fp32 [N,128] -> biased u8 (code = rint(v*127/m)+128), scale sx = m/127 ----------------
__global__ __launch_bounds__(256) void k_quant_x8(const float* __restrict__ x,
                                                  unsigned char* __restrict__ xq,
                                                  float* __restrict__ sx) {
    int t = threadIdx.x;
    int qw = t >> 4, ql = t & 15;
    int row = blockIdx.x * 16 + qw;
    if (row >= NN) return;
    const float4* p = (const float4*)(x + (size_t)row * 128 + ql * 8);
    float4 a = p[0], b = p[1];
    float v[8] = {a.x, a.y, a.z, a.w, b.x, b.y, b.z, b.w};
    float m = 0.f;
    #pragma unroll
    for (int k = 0; k < 8; ++k) m = fmaxf(m, fabsf(v[k]));
    m = fmaxf(m, __shfl_xor(m, 1));
    m = fmaxf(m, __shfl_xor(m, 2));
    m = fmaxf(m, __shfl_xor(m, 4));
    m = fmaxf(m, __shfl_xor(m, 8));
    float inv = (m > 0.f) ? 127.f / m : 0.f;
    unsigned w0 = 0, w1 = 0;
    #pragma unroll
    for (int k = 0; k < 4; ++k)
        w0 |= ((unsigned)((int)rintf(v[k] * inv) + 128) & 255u) << (8 * k);
    #pragma unroll
    for (int k = 0; k < 4; ++k)
        w1 |= ((unsigned)((int)rintf(v[4 + k] * inv) + 128) & 255u) << (8 * k);
    *(uint2*)(xq + (size_t)row * 128 + ql * 8) = make_uint2(w0, w1);
    if (ql == 0) sx[row] = (m > 0.f) ? m / 127.f : 0.f;
}

// ---------------- staged-batch helpers ----------------
// Load one 8-edge batch: colidx+scale from LDS (broadcast within group), payload from global.
template<int RSH>
static __device__ __forceinline__ void ld_batch(
    const unsigned char* __restrict__ qin,
    const int* __restrict__ cidxS, const float* __restrict__ scS,
    const int* __restrict__ colidx, const float* __restrict__ qs, bool inlds,
    int e, int end, int ebase, int li4,
    uint4 (&u)[8], float (&sc)[8])
{
    #pragma unroll
    for (int j = 0; j < 8; ++j) {
        const bool valid = (e + j < end);
        int sj = 0; float s = 0.f;
        if (valid) {
            if (inlds) { sj = cidxS[e + j - ebase]; s = scS[e + j - ebase]; }
            else       { sj = colidx[e + j];        s = qs[sj]; }
        }
        sc[j] = s;
        u[j] = *(const uint4*)(qin + (((unsigned)sj) << RSH) + li4);
    }
}

static __device__ __forceinline__ void acc_batch(
    const uint4 (&u)[8], const float (&sc)[8], float (&acc)[16], float& sum_sc)
{
    #pragma unroll
    for (int j = 0; j < 8; ++j) {
        #pragma unroll
        for (int wi = 0; wi < 4; ++wi) {
            unsigned w = (&u[j].x)[wi];
            acc[wi*4+0] = fmaf(sc[j], ubf(w, 0), acc[wi*4+0]);
            acc[wi*4+1] = fmaf(sc[j], ubf(w, 1), acc[wi*4+1]);
            acc[wi*4+2] = fmaf(sc[j], ubf(w, 2), acc[wi*4+2]);
            acc[wi*4+3] = fmaf(sc[j], ubf(w, 3), acc[wi*4+3]);
        }
        sum_sc += sc[j];
    }
}

// Cooperative staging: colidx (coalesced) then scales (independent gathers, depth-1 chain).
static __device__ __forceinline__ void stage_idx_sc(
    const int* __restrict__ colidx, const float* __restrict__ qs,
    int ebase, int etot, int t, int* cidxS, float* scS)
{
    int myidx[8];
    #pragma unroll
    for (int k = 0; k < 8; ++k) {
        int i = t + k * 256;
        myidx[k] = (i < etot) ? colidx[ebase + i] : 0;
    }
    #pragma unroll
    for (int k = 0; k < 8; ++k) {
        int i = t + k * 256;
        if (i < etot) { cidxS[i] = myidx[k]; scS[i] = qs[myidx[k]]; }
    }
}

// ---------------- layer 0: biased-u8 gather + dual MFMA + fused u8 quant output ----------------
__global__ __launch_bounds__(256, 3) void k_layer0(
    const unsigned char* __restrict__ xq, const float* __restrict__ sx,
    const float* __restrict__ xf,
    const ushort* __restrict__ Wl, const ushort* __restrict__ Wr,   // frag-major
    const float* __restrict__ bias, const float* __restrict__ invd,
    const int* __restrict__ rowptr, const int* __restrict__ colidx,
    unsigned char* __restrict__ hq, float* __restrict__ hs)          // u8 codes + scale
{
    __shared__ ushort aggS[64 * 128];   // 16KB
    __shared__ int cidxS[2048];         // 8KB
    __shared__ float scS[2048];         // 8KB
    char* aggSb = (char*)aggS;
    const int t  = threadIdx.x;
    const int r0 = blockIdx.x * 64;
    const int l = t & 63;

    const int ebase = rowptr[r0];
    const int rend  = (r0 + 64 < NN) ? (r0 + 64) : NN;
    const int etot  = rowptr[rend] - ebase;
    const bool inlds = (etot <= 2048);
    if (inlds) stage_idx_sc(colidx, sx, ebase, etot, t, cidxS, scS);
    __syncthreads();

    // ---- phase 1: 8 lanes per row, 2 rows serial per group, 2-deep pipelined batches ----
    {
        const int gid = t >> 3, li = t & 7;
        const int li4 = li << 4;
        for (int rr = gid; rr < 64; rr += 32) {
            const int r = r0 + rr;
            float acc[16];
            #pragma unroll
            for (int k = 0; k < 16; ++k) acc[k] = 0.f;
            float sum_sc = 0.f;
            if (r < NN) {
                const int beg = rowptr[r], end = rowptr[r + 1];
                if (beg < end) {
                    uint4 uA[8], uB[8];
                    float scA[8], scB[8];
                    ld_batch<7>(xq, cidxS, scS, colidx, sx, inlds, beg, end, ebase, li4, uA, scA);
                    for (int e = beg; e < end; e += 16) {
                        const bool hasB = (e + 8 < end);
                        if (hasB)
                            ld_batch<7>(xq, cidxS, scS, colidx, sx, inlds, e + 8, end, ebase, li4, uB, scB);
                        acc_batch(uA, scA, acc, sum_sc);
                        if (e + 16 < end)
                            ld_batch<7>(xq, cidxS, scS, colidx, sx, inlds, e + 16, end, ebase, li4, uA, scA);
                        if (hasB) acc_batch(uB, scB, acc, sum_sc);
                    }
                }
                const float iv = invd[r];
                #pragma unroll
                for (int k = 0; k < 16; ++k) acc[k] = (acc[k] - 128.f * sum_sc) * iv;
            }
            #pragma unroll
            for (int gg = 0; gg < 2; ++gg) {
                unsigned q0 = (unsigned)f2bf(acc[gg*8+0]) | ((unsigned)f2bf(acc[gg*8+1]) << 16);
                unsigned q1 = (unsigned)f2bf(acc[gg*8+2]) | ((unsigned)f2bf(acc[gg*8+3]) << 16);
                unsigned q2 = (unsigned)f2bf(acc[gg*8+4]) | ((unsigned)f2bf(acc[gg*8+5]) << 16);
                unsigned q3 = (unsigned)f2bf(acc[gg*8+6]) | ((unsigned)f2bf(acc[gg*8+7]) << 16);
                int g  = li * 2 + gg;
                int gs = g ^ (rr & 7);
                *(uint4*)(aggSb + (size_t)rr * 256 + (gs << 4)) = make_uint4(q0, q1, q2, q3);
            }
        }
    }
    __syncthreads();

    // ---- phase 2: kk-outer dual MFMA, acc[16] chunks ----
    const int w = t >> 6, lm = l & 15, lk = l >> 4;
    const int rr = w * 16 + lm;
    const int rg = r0 + rr;

    bf16x8 ax[4];
    #pragma unroll
    for (int kk = 0; kk < 4; ++kk) {
        bf16x8 v;
        if (rg < NN) {
            const float4* p = (const float4*)(xf + (size_t)rg * 128 + kk * 32 + lk * 8);
            float4 f0 = p[0], f1 = p[1];
            v[0] = (short)f2bf(f0.x); v[1] = (short)f2bf(f0.y);
            v[2] = (short)f2bf(f0.z); v[3] = (short)f2bf(f0.w);
            v[4] = (short)f2bf(f1.x); v[5] = (short)f2bf(f1.y);
            v[6] = (short)f2bf(f1.z); v[7] = (short)f2bf(f1.w);
        } else v = (bf16x8)(short)0;
        ax[kk] = v;
    }
    bf16x8 agg_reg[4];
    #pragma unroll
    for (int kk = 0; kk < 4; ++kk) {
        int g  = kk * 4 + lk;
        int gs = g ^ (rr & 7);
        agg_reg[kk] = *(const bf16x8*)(aggSb + (size_t)rr * 256 + (gs << 4));
    }

    f32x4 acc[16];
    #pragma unroll
    for (int cc = 0; cc < 16; ++cc) acc[cc] = {0.f, 0.f, 0.f, 0.f};

    #pragma unroll
    for (int kk = 0; kk < 4; ++kk) {
        #pragma unroll
        for (int cc = 0; cc < 16; ++cc) {
            const size_t wf = ((size_t)(cc * 4 + kk) * 64 + l) * 8;
            bf16x8 bl = *(const bf16x8*)(Wl + wf);
            bf16x8 br = *(const bf16x8*)(Wr + wf);
            acc[cc] = __builtin_amdgcn_mfma_f32_16x16x32_bf16(agg_reg[kk], bl, acc[cc], 0, 0, 0);
            acc[cc] = __builtin_amdgcn_mfma_f32_16x16x32_bf16(ax[kk],      br, acc[cc], 0, 0, 0);
        }
    }

    // epilogue: bias+relu in place, per-row max, u8 quantize
    float vmax[4] = {0.f, 0.f, 0.f, 0.f};
    #pragma unroll
    for (int cc = 0; cc < 16; ++cc) {
        const float bv = bias[cc * 16 + lm];
        #pragma unroll
        for (int i = 0; i < 4; ++i) {
            float v = fmaxf(acc[cc][i] + bv, 0.f);
            acc[cc][i] = v;
            vmax[i] = fmaxf(vmax[i], v);
        }
    }
    #pragma unroll
    for (int i = 0; i < 4; ++i) {
        vmax[i] = fmaxf(vmax[i], __shfl_xor(vmax[i], 1));
        vmax[i] = fmaxf(vmax[i], __shfl_xor(vmax[i], 2));
        vmax[i] = fmaxf(vmax[i], __shfl_xor(vmax[i], 4));
        vmax[i] = fmaxf(vmax[i], __shfl_xor(vmax[i], 8));
    }
    float invq[4];
    #pragma unroll
    for (int i = 0; i < 4; ++i) invq[i] = (vmax[i] > 0.f) ? 255.f / vmax[i] : 0.f;
    const int ob = r0 + w * 16 + lk * 4;
    if (lm == 0) {
        #pragma unroll
        for (int i = 0; i < 4; ++i)
            if (ob + i < NN) hs[ob + i] = vmax[i] / 255.f;
    }
    #pragma unroll
    for (int cc = 0; cc < 16; ++cc) {
        #pragma unroll
        for (int i = 0; i < 4; ++i) {
            if (ob + i < NN)
                hq[(size_t)(ob + i) * 256 + cc * 16 + lm] =
                    (unsigned char)(int)rintf(acc[cc][i] * invq[i]);
        }
    }
}

// ---------------- layer 1: u8 gather + dual MFMA -> h1 bf16 ----------------
__global__ __launch_bounds__(256, 3) void k_layer1(
    const unsigned char* __restrict__ hq, const float* __restrict__ hs,
    const ushort* __restrict__ Wl, const ushort* __restrict__ Wr,   // frag-major
    const float* __restrict__ bias, const float* __restrict__ invd,
    const int* __restrict__ rowptr, const int* __restrict__ colidx,
    ushort* __restrict__ hout)
{
    __shared__ ushort aggS[64 * 256];   // 32KB
    __shared__ int cidxS[2048];         // 8KB
    __shared__ float scS[2048];         // 8KB
    char* aggSb = (char*)aggS;
    const int t  = threadIdx.x;
    const int r0 = blockIdx.x * 64;
    const int l = t & 63;

    const int ebase = rowptr[r0];
    const int rend  = (r0 + 64 < NN) ? (r0 + 64) : NN;
    const int etot  = rowptr[rend] - ebase;
    const bool inlds = (etot <= 2048);
    if (inlds) stage_idx_sc(colidx, hs, ebase, etot, t, cidxS, scS);
    __syncthreads();

    // ---- phase 1: 16 lanes per row, 4 rows serial per group, 2-deep pipelined ----
    {
        const int gid = t >> 4, li = t & 15;
        const int li4 = li << 4;
        for (int rr = gid; rr < 64; rr += 16) {
            const int r = r0 + rr;
            float acc[16];
            #pragma unroll
            for (int k = 0; k < 16; ++k) acc[k] = 0.f;
            float sum_sc = 0.f;
            if (r < NN) {
                const int beg = rowptr[r], end = rowptr[r + 1];
                if (beg < end) {
                    uint4 uA[8], uB[8];
                    float scA[8], scB[8];
                    ld_batch<8>(hq, cidxS, scS, colidx, hs, inlds, beg, end, ebase, li4, uA, scA);
                    for (int e = beg; e < end; e += 16) {
                        const bool hasB = (e + 8 < end);
                        if (hasB)
                            ld_batch<8>(hq, cidxS, scS, colidx, hs, inlds, e + 8, end, ebase, li4, uB, scB);
                        acc_batch(uA, scA, acc, sum_sc);
                        if (e + 16 < end)
                            ld_batch<8>(hq, cidxS, scS, colidx, hs, inlds, e + 16, end, ebase, li4, uA, scA);
                        if (hasB) acc_batch(uB, scB, acc, sum_sc);
                    }
                }
                const float iv = invd[r];
                #pragma unroll
                for (int k = 0; k < 16; ++k) acc[k] *= iv;
            }
            #pragma unroll
            for (int gg = 0; gg < 2; ++gg) {
                unsigned q0 = (unsigned)f2bf(acc[gg*8+0]) | ((unsigned)f2bf(acc[gg*8+1]) << 16);
                unsigned q1 = (unsigned)f2bf(acc[gg*8+2]) | ((unsigned)f2bf(acc[gg*8+3]) << 16);
                unsigned q2 = (unsigned)f2bf(acc[gg*8+4]) | ((unsigned)f2bf(acc[gg*8+5]) << 16);
                unsigned q3 = (unsigned)f2bf(acc[gg*8+6]) | ((unsigned)f2bf(acc[gg*8+7]) << 16);
                int g  = li * 2 + gg;
                int gs = g ^ (rr & 7);
                *(uint4*)(aggSb + (size_t)rr * 512 + (gs << 4)) = make_uint4(q0, q1, q2, q3);
            }
        }
    }
    __syncthreads();

    // ---- phase 2: frag-hoisted dual MFMA over HID in 16-col chunks ----
    const int w = t >> 6, lm = l & 15, lk = l >> 4;
    const int rr = w * 16 + lm;
    const int rg = r0 + rr;

    bf16x8 ax[8];
    {
        const float sr = (rg < NN) ? hs[rg] : 0.f;
        #pragma unroll
        for (int kk = 0; kk < 8; ++kk) {
            uint2 uq = (rg < NN)
                ? *(const uint2*)(hq + (((unsigned)rg) << 8) + kk * 32 + lk * 8)
                : make_uint2(0u, 0u);
            bf16x8 v;
            v[0] = (short)f2bf(sr * ubf(uq.x, 0));
            v[1] = (short)f2bf(sr * ubf(uq.x, 1));
            v[2] = (short)f2bf(sr * ubf(uq.x, 2));
            v[3] = (short)f2bf(sr * ubf(uq.x, 3));
            v[4] = (short)f2bf(sr * ubf(uq.y, 0));
            v[5] = (short)f2bf(sr * ubf(uq.y, 1));
            v[6] = (short)f2bf(sr * ubf(uq.y, 2));
            v[7] = (short)f2bf(sr * ubf(uq.y, 3));
            ax[kk] = v;
        }
    }
    bf16x8 agg_reg[8];
    #pragma unroll
    for (int kk = 0; kk < 8; ++kk) {
        int g  = kk * 4 + lk;
        int gs = g ^ (rr & 7);
        agg_reg[kk] = *(const bf16x8*)(aggSb + (size_t)rr * 512 + (gs << 4));
    }

    for (int cc = 0; cc < 16; ++cc) {
        const int c = cc * 16 + lm;
        f32x4 acc = {0.f, 0.f, 0.f, 0.f};
        #pragma unroll
        for (int kk = 0; kk < 8; ++kk) {
            const size_t wf = ((size_t)(cc * 8 + kk) * 64 + l) * 8;
            bf16x8 bl = *(const bf16x8*)(Wl + wf);
            bf16x8 br = *(const bf16x8*)(Wr + wf);
            acc = __builtin_amdgcn_mfma_f32_16x16x32_bf16(agg_reg[kk], bl, acc, 0, 0, 0);
            acc = __builtin_amdgcn_mfma_f32_16x16x32_bf16(ax[kk],      br, acc, 0, 0, 0);
        }
        const float bv = bias[c];
        #pragma unroll
        for (int i = 0; i < 4; ++i) {
            const int orow = r0 + w * 16 + lk * 4 + i;
            if (orow < NN) {
                float v = fmaxf(acc[i] + bv, 0.f);
                hout[(size_t)orow * HID + c] = f2bf(v);
            }
        }
    }
}

// ---------------- premul: qq = biased-u8(h1@Wlo^T)+sq, rbuf = h1@Wro^T+bo ----------------
__global__ __launch_bounds__(256, 4) void k_premul(
    const ushort* __restrict__ h1, const ushort* __restrict__ wlo,
    const ushort* __restrict__ wro, const float* __restrict__ bo,
    unsigned char* __restrict__ qq, float* __restrict__ sq, float* __restrict__ rbuf)
{
    const int t = threadIdx.x;
    const int r0 = blockIdx.x * 64;
    const int w = t >> 6, l = t & 63, lm = l & 15, lk = l >> 4;
    const int rr = w * 16 + lm;
    const int rg = r0 + rr;

    f32x4 aq[3], ar[3];
    #pragma unroll
    for (int cc = 0; cc < 3; ++cc) { aq[cc] = {0.f,0.f,0.f,0.f}; ar[cc] = {0.f,0.f,0.f,0.f}; }

    #pragma unroll
    for (int kk = 0; kk < 8; ++kk) {
        bf16x8 a = (rg < NN)
            ? *(const bf16x8*)(h1 + (size_t)rg * 256 + kk * 32 + lk * 8)
            : (bf16x8)(short)0;
        #pragma unroll
        for (int cc = 0; cc < 3; ++cc) {
            const size_t wf = ((size_t)(cc * 8 + kk) * 64 + l) * 8;
            bf16x8 bl = *(const bf16x8*)(wlo + wf);
            bf16x8 br = *(const bf16x8*)(wro + wf);
            aq[cc] = __builtin_amdgcn_mfma_f32_16x16x32_bf16(a, bl, aq[cc], 0, 0, 0);
            ar[cc] = __builtin_amdgcn_mfma_f32_16x16x32_bf16(a, br, ar[cc], 0, 0, 0);
        }
    }

    #pragma unroll
    for (int i = 0; i < 4; ++i) {
        const int orow = r0 + w * 16 + lk * 4 + i;
        if (orow >= NN) continue;
        float m = 0.f;
        #pragma unroll
        for (int cc = 0; cc < 3; ++cc) {
            const int c = cc * 16 + lm;
            if (c < OUTC) m = fmaxf(m, fabsf(aq[cc][i]));
        }
        m = fmaxf(m, __shfl_xor(m, 1));
        m = fmaxf(m, __shfl_xor(m, 2));
        m = fmaxf(m, __shfl_xor(m, 4));
        m = fmaxf(m, __shfl_xor(m, 8));
        const float inv = (m > 0.f) ? 127.f / m : 0.f;
        #pragma unroll
        for (int cc = 0; cc < 3; ++cc) {
            const int c = cc * 16 + lm;
            int code = (c < OUTC) ? (int)rintf(aq[cc][i] * inv) : 0;
            qq[(size_t)orow * 64 + c] = (unsigned char)(code + 128);
            rbuf[(size_t)orow * 64 + c] = (c < OUTC) ? (ar[cc][i] + bo[c]) : 0.f;
        }
        qq[(size_t)orow * 64 + 48 + lm] = (unsigned char)128;
        rbuf[(size_t)orow * 64 + 48 + lm] = 0.f;
        if (lm == 0) sq[orow] = m / 127.f;
    }
}

// ---------------- final: out = log_softmax(mean_agg(q) + r), 4 lanes per row ----------------
__global__ __launch_bounds__(256) void k_final(
    const unsigned char* __restrict__ qq, const float* __restrict__ sq,
    const float* __restrict__ rbuf, const float* __restrict__ invd,
    const int* __restrict__ rowptr, const int* __restrict__ colidx,
    float* __restrict__ out)
{
    __shared__ int cidxS[2048];
    __shared__ float scS[2048];
    const int t = threadIdx.x;
    const int g = t >> 2, li = t & 3;
    const int li4 = li << 4;
    const int r0 = blockIdx.x * 64;
    const int row = r0 + g;

    const int ebase = rowptr[r0];
    const int rend  = (r0 + 64 < NN) ? (r0 + 64) : NN;
    const int etot  = rowptr[rend] - ebase;
    const bool inlds = (etot <= 2048);
    if (inlds) stage_idx_sc(colidx, sq, ebase, etot, t, cidxS, scS);
    __syncthreads();
    if (row >= NN) return;

    float acc[16];
    #pragma unroll
    for (int k = 0; k < 16; ++k) acc[k] = 0.f;
    float sum_sc = 0.f;

    const int beg = rowptr[row], end = rowptr[row + 1];
    if (beg < end) {
        uint4 uA[8], uB[8];
        float scA[8], scB[8];
        ld_batch<6>(qq, cidxS, scS, colidx, sq, inlds, beg, end, ebase, li4, uA, scA);
        for (int e = beg; e < end; e += 16) {
            const bool hasB = (e + 8 < end);
            if (hasB)
                ld_batch<6>(qq, cidxS, scS, colidx, sq, inlds, e + 8, end, ebase, li4, uB, scB);
            acc_batch(uA, scA, acc, sum_sc);
            if (e + 16 < end)
                ld_batch<6>(qq, cidxS, scS, colidx, sq, inlds, e + 16, end, ebase, li4, uA, scA);
            if (hasB) acc_batch(uB, scB, acc, sum_sc);
        }
    }

    const float iv = invd[row];
    const float4* rp = (const float4*)(rbuf + (size_t)row * 64 + li * 16);
    float v[16];
    #pragma unroll
    for (int ch = 0; ch < 4; ++ch) {
        float4 rv = rp[ch];
        v[ch*4+0] = (acc[ch*4+0] - 128.f * sum_sc) * iv + rv.x;
        v[ch*4+1] = (acc[ch*4+1] - 128.f * sum_sc) * iv + rv.y;
        v[ch*4+2] = (acc[ch*4+2] - 128.f * sum_sc) * iv + rv.z;
        v[ch*4+3] = (acc[ch*4+3] - 128.f * sum_sc) * iv + rv.w;
    }
    #pragma unroll
    for (int k = 0; k < 16; ++k)
        if (li * 16 + k >= OUTC) v[k] = -INFINITY;

    float m = v[0];
    #pragma unroll
    for (int k = 1; k < 16; ++k) m = fmaxf(m, v[k]);
    m = fmaxf(m, __shfl_xor(m, 1));
    m = fmaxf(m, __shfl_xor(m, 2));

    float s = 0.f;
    #pragma unroll
    for (int k = 0; k < 16; ++k)
        if (li * 16 + k < OUTC) s += __expf(v[k] - m);
    s += __shfl_xor(s, 1);
    s += __shfl_xor(s, 2);
    const float ls = __logf(s);

    #pragma unroll
    for (int ch = 0; ch < 4; ++ch) {
        const int c = li * 16 + ch * 4;
        if (c < OUTC) {
            float4 o;
            o.x = v[ch*4+0] - m - ls;
            o.y = v[ch*4+1] - m - ls;
            o.z = v[ch*4+2] - m - ls;
            o.w = v[ch*4+3] - m - ls;
            *(float4*)(out + (size_t)row * OUTC + c) = o;
        }
    }
}

extern "C" void kernel_launch(void* const* d_in, const int* in_sizes, int n_in,
                              void* d_out, int out_size, void* d_ws, size_t ws_size,
                              hipStream_t stream) {
    const float* x   = (const float*)d_in[0];
    const int*   ei  = (const int*)d_in[1];
    const int*   src = ei;
    const int*   dst = ei + NE;
    const float* Wl0 = (const float*)d_in[2];
    const float* Wr0 = (const float*)d_in[3];
    const float* b0  = (const float*)d_in[4];
    const float* Wl1 = (const float*)d_in[5];
    const float* Wr1 = (const float*)d_in[6];
    const float* b1  = (const float*)d_in[7];
    const float* Wlo = (const float*)d_in[8];
    const float* Wro = (const float*)d_in[9];
    const float* bo  = (const float*)d_in[10];
    float* out = (float*)d_out;

    char* ws = (char*)d_ws;
    const size_t MB = 1 << 20;
    float*         invd   = (float*)(ws + 0);
    int*           rowptr = (int*)(ws + MB / 2);
    int*           cnt    = (int*)(ws + MB);
    int*           fillp  = (int*)(ws + MB + MB / 2);
    int*           bsum   = (int*)(ws + 2 * MB);
    int*           boff   = (int*)(ws + 2 * MB + MB / 4);
    float*         sx     = (float*)(ws + 2 * MB + MB / 2);
    float*         s0     = (float*)(ws + 3 * MB);
    float*         sq     = (float*)(ws + 3 * MB + MB / 2);
    ushort*        Wb     = (ushort*)(ws + 4 * MB);            // 442KB frag-major
    int*           colidx = (int*)(ws + 4 * MB + MB / 2);      // 6.4MB -> ends ~10.9
    unsigned char* xq8    = (unsigned char*)(ws + 11 * MB);    // [N,128] u8 = 12.8MB (11..23.8)
    unsigned char* qq     = (unsigned char*)(ws + 11 * MB);    // aliases xq8 (dead after layer0)
    unsigned char* h0q    = (unsigned char*)(ws + 24 * MB);    // [N,256] u8 = 25.6MB (24..49.6)
    float*         rbuf   = (float*)(ws + 24 * MB);            // aliases h0q (h0q dead after layer1)
    ushort*        h1     = (ushort*)(ws + 50 * MB);           // [N,256] bf16 = 51.2MB (50..101.2)

    ushort* wl0 = Wb;                 // 16*4*64*8  = 32768
    ushort* wr0 = Wb + 32768;
    ushort* wl1 = Wb + 65536;         // 16*8*64*8  = 65536
    ushort* wr1 = Wb + 131072;
    ushort* wlo = Wb + 196608;        // 3*8*64*8   = 12288 (48-row zero-padded)
    ushort* wro = Wb + 208896;

    // CSR build
    hipMemsetAsync(cnt, 0, NN * sizeof(int), stream);
    k_count<<<(NE + 255) / 256, 256, 0, stream>>>(dst, cnt);
    const int NB = (NN + 255) / 256;  // 391
    k_blocksum<<<NB, 256, 0, stream>>>(cnt, bsum);
    k_scanblock<<<1, 512, 0, stream>>>(bsum, boff, NB);
    k_rowptr<<<NB, 256, 0, stream>>>(cnt, boff, rowptr, fillp, invd);
    k_fill<<<(NE + 255) / 256, 256, 0, stream>>>(src, dst, fillp, colidx);

    // weights -> fragment-major bf16; x -> biased u8
    k_cvtfrag<<<16, 256, 0, stream>>>(Wl0, wl0, 256, 128, 4096);
    k_cvtfrag<<<16, 256, 0, stream>>>(Wr0, wr0, 256, 128, 4096);
    k_cvtfrag<<<32, 256, 0, stream>>>(Wl1, wl1, 256, 256, 8192);
    k_cvtfrag<<<32, 256, 0, stream>>>(Wr1, wr1, 256, 256, 8192);
    k_cvtfrag<<<6,  256, 0, stream>>>(Wlo, wlo, 40, 256, 1536);
    k_cvtfrag<<<6,  256, 0, stream>>>(Wro, wro, 40, 256, 1536);
    k_quant_x8<<<(NN + 15) / 16, 256, 0, stream>>>(x, xq8, sx);

    const int GB = (NN + 63) / 64;  // 1563
    // layer 0 (fused u8-quant output): gather biased-u8 x, self fp32 x -> h0q u8 + s0
    k_layer0<<<GB, 256, 0, stream>>>(xq8, sx, x, wl0, wr0, b0, invd, rowptr, colidx, h0q, s0);
    // layer 1: gather u8 h0, self u8 h0 -> h1 bf16
    k_layer1<<<GB, 256, 0, stream>>>(h0q, s0, wl1, wr1, b1, invd, rowptr, colidx, h1);
    // premul: h1 -> qq (biased u8), sq, rbuf
    k_premul<<<GB, 256, 0, stream>>>(h1, wlo, wro, bo, qq, sq, rbuf);
    // final: 1-line-per-edge gather + log_softmax
    k_final<<<GB, 256, 0, stream>>>(qq, sq, rbuf, invd, rowptr, colidx, out);
}

// Round 15
// 508.567 us; speedup vs baseline: 1.2319x; 1.2319x over previous
//
#include <hip/hip_runtime.h>
#include <hip/hip_bf16.h>
#include <cstdint>
#include <cstddef>

#define NN   100000
#define NE   1600000
#define HID  256
#define OUTC 40

typedef __attribute__((ext_vector_type(8))) short bf16x8;
typedef __attribute__((ext_vector_type(4))) float f32x4;

static __device__ __forceinline__ ushort f2bf(float f) {
    __hip_bfloat16 h = __float2bfloat16(f);
    return *reinterpret_cast<ushort*>(&h);
}
static __device__ __forceinline__ float bflo(unsigned u) { return __uint_as_float(u << 16); }
static __device__ __forceinline__ float bfhi(unsigned u) { return __uint_as_float(u & 0xffff0000u); }
// unsigned byte k of word w -> float (selects to v_cvt_f32_ubyteN)
static __device__ __forceinline__ float ubf(unsigned w, int k) {
    return (float)((w >> (8 * k)) & 255u);
}

// ---------------- CSR build ----------------
__global__ void k_count(const int* __restrict__ dst, int* __restrict__ cnt) {
    int i = blockIdx.x * blockDim.x + threadIdx.x;
    if (i < NE) atomicAdd(&cnt[dst[i]], 1);
}

__global__ void k_blocksum(const int* __restrict__ cnt, int* __restrict__ bsum) {
    __shared__ int s[256];
    int t = threadIdx.x;
    int n = blockIdx.x * 256 + t;
    s[t] = (n < NN) ? cnt[n] : 0;
    __syncthreads();
    for (int off = 128; off; off >>= 1) {
        if (t < off) s[t] += s[t + off];
        __syncthreads();
    }
    if (t == 0) bsum[blockIdx.x] = s[0];
}

__global__ void k_scanblock(const int* __restrict__ bsum, int* __restrict__ boff, int nb) {
    __shared__ int s[512];
    int t = threadIdx.x;
    int v = (t < nb) ? bsum[t] : 0;
    s[t] = v;
    __syncthreads();
    for (int off = 1; off < 512; off <<= 1) {
        int u = (t >= off) ? s[t - off] : 0;
        __syncthreads();
        s[t] += u;
        __syncthreads();
    }
    if (t < nb) boff[t] = s[t] - v;
}

__global__ void k_rowptr(const int* __restrict__ cnt, const int* __restrict__ boff,
                         int* __restrict__ rowptr, int* __restrict__ fillp,
                         float* __restrict__ invd) {
    __shared__ int s[256];
    int t = threadIdx.x;
    int n = blockIdx.x * 256 + t;
    int c = (n < NN) ? cnt[n] : 0;
    s[t] = c;
    __syncthreads();
    for (int off = 1; off < 256; off <<= 1) {
        int u = (t >= off) ? s[t - off] : 0;
        __syncthreads();
        s[t] += u;
        __syncthreads();
    }
    if (n < NN) {
        int excl = boff[blockIdx.x] + s[t] - c;
        rowptr[n] = excl;
        fillp[n]  = excl;
        invd[n]   = 1.0f / (float)(c > 1 ? c : 1);
    }
    if (n == 0) rowptr[NN] = NE;
}

__global__ void k_fill(const int* __restrict__ src, const int* __restrict__ dst,
                       int* __restrict__ fillp, int* __restrict__ colidx) {
    int i = blockIdx.x * blockDim.x + threadIdx.x;
    if (i < NE) {
        int p = atomicAdd(&fillp[dst[i]], 1);
        colidx[p] = src[i];
    }
}

// ---------------- weights fp32 [OC][D] -> fragment-major bf16 ----------------
__global__ void k_cvtfrag(const float* __restrict__ W, ushort* __restrict__ dst,
                          int ocreal, int d, int nf) {
    int f = blockIdx.x * 256 + threadIdx.x;
    if (f >= nf) return;
    int lm = f & 15, lk = (f >> 4) & 3;
    int rest = f >> 6;
    int dk = d / 32;
    int kk = rest % dk, cc = rest / dk;
    int row = cc * 16 + lm, col = kk * 32 + lk * 8;
    unsigned q0 = 0, q1 = 0, q2 = 0, q3 = 0;
    if (row < ocreal) {
        const float4* p = (const float4*)(W + (size_t)row * d + col);
        float4 a = p[0], b = p[1];
        q0 = (unsigned)f2bf(a.x) | ((unsigned)f2bf(a.y) << 16);
        q1 = (unsigned)f2bf(a.z) | ((unsigned)f2bf(a.w) << 16);
        q2 = (unsigned)f2bf(b.x) | ((unsigned)f2bf(b.y) << 16);
        q3 = (unsigned)f2bf(b.z) | ((unsigned)f2bf(b.w) << 16);
    }
    *(uint4*)(dst + (size_t)f * 8) = make_uint4(q0, q1, q2, q3);
}

// ---------------- x fp32 [N,128] -> biased u8 (code = rint(v*127/m)+128), scale sx = m/127 ----------------
__global__ __launch_bounds__(256) void k_quant_x8(const float* __restrict__ x,
                                                  unsigned char* __restrict__ xq,
                                                  float* __restrict__ sx) {
    int t = threadIdx.x;
    int qw = t >> 4, ql = t & 15;
    int row = blockIdx.x * 16 + qw;
    if (row >= NN) return;
    const float4* p = (const float4*)(x + (size_t)row * 128 + ql * 8);
    float4 a = p[0], b = p[1];
    float v[8] = {a.x, a.y, a.z, a.w, b.x, b.y, b.z, b.w};
    float m = 0.f;
    #pragma unroll
    for (int k = 0; k < 8; ++k) m = fmaxf(m, fabsf(v[k]));
    m = fmaxf(m, __shfl_xor(m, 1));
    m = fmaxf(m, __shfl_xor(m, 2));
    m = fmaxf(m, __shfl_xor(m, 4));
    m = fmaxf(m, __shfl_xor(m, 8));
    float inv = (m > 0.f) ? 127.f / m : 0.f;
    unsigned w0 = 0, w1 = 0;
    #pragma unroll
    for (int k = 0; k < 4; ++k)
        w0 |= ((unsigned)((int)rintf(v[k] * inv) + 128) & 255u) << (8 * k);
    #pragma unroll
    for (int k = 0; k < 4; ++k)
        w1 |= ((unsigned)((int)rintf(v[4 + k] * inv) + 128) & 255u) << (8 * k);
    *(uint2*)(xq + (size_t)row * 128 + ql * 8) = make_uint2(w0, w1);
    if (ql == 0) sx[row] = (m > 0.f) ? m / 127.f : 0.f;
}

// ---------------- layer 0: biased-u8 gather + dual MFMA + fused u8 quant output ----------------
__global__ __launch_bounds__(256, 4) void k_layer0(
    const unsigned char* __restrict__ xq, const float* __restrict__ sx,
    const float* __restrict__ xf,
    const ushort* __restrict__ Wl, const ushort* __restrict__ Wr,   // frag-major
    const float* __restrict__ bias, const float* __restrict__ invd,
    const int* __restrict__ rowptr, const int* __restrict__ colidx,
    unsigned char* __restrict__ hq, float* __restrict__ hs)          // u8 codes + scale
{
    __shared__ ushort aggS[64 * 128];   // 16KB
    __shared__ int cidxS[2048];         // 8KB
    char* aggSb = (char*)aggS;
    const int t  = threadIdx.x;
    const int r0 = blockIdx.x * 64;
    const int l = t & 63;

    // stage block's colidx range into LDS
    const int ebase = rowptr[r0];
    const int rend  = (r0 + 64 < NN) ? (r0 + 64) : NN;
    const int etot  = rowptr[rend] - ebase;
    const bool inlds = (etot <= 2048);
    if (inlds) {
        for (int i = t; i < etot; i += 256) cidxS[i] = colidx[ebase + i];
    }
    __syncthreads();

    // ---- phase 1: 8 lanes per row, 2 rows serial per group ----
    {
        const int gid = t >> 3, li = t & 7;
        const int base = l & ~7;
        for (int rr = gid; rr < 64; rr += 32) {
            const int r = r0 + rr;
            float acc[16];
            #pragma unroll
            for (int k = 0; k < 16; ++k) acc[k] = 0.f;
            float sum_sc = 0.f;
            if (r < NN) {
                const int beg = rowptr[r], end = rowptr[r + 1];
                for (int e = beg; e < end; e += 8) {
                    const int myi = e + li;
                    int se = -1;
                    if (myi < end) se = inlds ? cidxS[myi - ebase] : colidx[myi];
                    float mysc = (se >= 0) ? sx[se] : 0.f;
                    int   sj[8];
                    float sc[8];
                    uint4 u[8];
                    #pragma unroll
                    for (int j = 0; j < 8; ++j) sj[j] = __shfl(se, base + j);
                    #pragma unroll
                    for (int j = 0; j < 8; ++j) sc[j] = __shfl(mysc, base + j);
                    #pragma unroll
                    for (int j = 0; j < 8; ++j) {
                        u[j] = (sj[j] >= 0)
                            ? *(const uint4*)(xq + (((unsigned)sj[j]) << 7) + (li << 4))
                            : make_uint4(0u, 0u, 0u, 0u);
                    }
                    #pragma unroll
                    for (int j = 0; j < 8; ++j) {
                        #pragma unroll
                        for (int wi = 0; wi < 4; ++wi) {
                            unsigned w = (&u[j].x)[wi];
                            acc[wi*4+0] = fmaf(sc[j], ubf(w, 0), acc[wi*4+0]);
                            acc[wi*4+1] = fmaf(sc[j], ubf(w, 1), acc[wi*4+1]);
                            acc[wi*4+2] = fmaf(sc[j], ubf(w, 2), acc[wi*4+2]);
                            acc[wi*4+3] = fmaf(sc[j], ubf(w, 3), acc[wi*4+3]);
                        }
                        sum_sc += sc[j];
                    }
                }
                const float iv = invd[r];
                #pragma unroll
                for (int k = 0; k < 16; ++k) acc[k] = (acc[k] - 128.f * sum_sc) * iv;
            }
            #pragma unroll
            for (int gg = 0; gg < 2; ++gg) {
                unsigned q0 = (unsigned)f2bf(acc[gg*8+0]) | ((unsigned)f2bf(acc[gg*8+1]) << 16);
                unsigned q1 = (unsigned)f2bf(acc[gg*8+2]) | ((unsigned)f2bf(acc[gg*8+3]) << 16);
                unsigned q2 = (unsigned)f2bf(acc[gg*8+4]) | ((unsigned)f2bf(acc[gg*8+5]) << 16);
                unsigned q3 = (unsigned)f2bf(acc[gg*8+6]) | ((unsigned)f2bf(acc[gg*8+7]) << 16);
                int g  = li * 2 + gg;
                int gs = g ^ (rr & 7);
                *(uint4*)(aggSb + (size_t)rr * 256 + (gs << 4)) = make_uint4(q0, q1, q2, q3);
            }
        }
    }
    __syncthreads();

    // ---- phase 2: kk-outer dual MFMA, acc[16] chunks ----
    const int w = t >> 6, lm = l & 15, lk = l >> 4;
    const int rr = w * 16 + lm;
    const int rg = r0 + rr;

    bf16x8 ax[4];
    #pragma unroll
    for (int kk = 0; kk < 4; ++kk) {
        bf16x8 v;
        if (rg < NN) {
            const float4* p = (const float4*)(xf + (size_t)rg * 128 + kk * 32 + lk * 8);
            float4 f0 = p[0], f1 = p[1];
            v[0] = (short)f2bf(f0.x); v[1] = (short)f2bf(f0.y);
            v[2] = (short)f2bf(f0.z); v[3] = (short)f2bf(f0.w);
            v[4] = (short)f2bf(f1.x); v[5] = (short)f2bf(f1.y);
            v[6] = (short)f2bf(f1.z); v[7] = (short)f2bf(f1.w);
        } else v = (bf16x8)(short)0;
        ax[kk] = v;
    }
    bf16x8 agg_reg[4];
    #pragma unroll
    for (int kk = 0; kk < 4; ++kk) {
        int g  = kk * 4 + lk;
        int gs = g ^ (rr & 7);
        agg_reg[kk] = *(const bf16x8*)(aggSb + (size_t)rr * 256 + (gs << 4));
    }

    f32x4 acc[16];
    #pragma unroll
    for (int cc = 0; cc < 16; ++cc) acc[cc] = {0.f, 0.f, 0.f, 0.f};

    #pragma unroll
    for (int kk = 0; kk < 4; ++kk) {
        #pragma unroll
        for (int cc = 0; cc < 16; ++cc) {
            const size_t wf = ((size_t)(cc * 4 + kk) * 64 + l) * 8;
            bf16x8 bl = *(const bf16x8*)(Wl + wf);
            bf16x8 br = *(const bf16x8*)(Wr + wf);
            acc[cc] = __builtin_amdgcn_mfma_f32_16x16x32_bf16(agg_reg[kk], bl, acc[cc], 0, 0, 0);
            acc[cc] = __builtin_amdgcn_mfma_f32_16x16x32_bf16(ax[kk],      br, acc[cc], 0, 0, 0);
        }
    }

    // epilogue: bias+relu in place, per-row max, u8 quantize
    float vmax[4] = {0.f, 0.f, 0.f, 0.f};
    #pragma unroll
    for (int cc = 0; cc < 16; ++cc) {
        const float bv = bias[cc * 16 + lm];
        #pragma unroll
        for (int i = 0; i < 4; ++i) {
            float v = fmaxf(acc[cc][i] + bv, 0.f);
            acc[cc][i] = v;
            vmax[i] = fmaxf(vmax[i], v);
        }
    }
    #pragma unroll
    for (int i = 0; i < 4; ++i) {
        vmax[i] = fmaxf(vmax[i], __shfl_xor(vmax[i], 1));
        vmax[i] = fmaxf(vmax[i], __shfl_xor(vmax[i], 2));
        vmax[i] = fmaxf(vmax[i], __shfl_xor(vmax[i], 4));
        vmax[i] = fmaxf(vmax[i], __shfl_xor(vmax[i], 8));
    }
    float invq[4];
    #pragma unroll
    for (int i = 0; i < 4; ++i) invq[i] = (vmax[i] > 0.f) ? 255.f / vmax[i] : 0.f;
    const int ob = r0 + w * 16 + lk * 4;
    if (lm == 0) {
        #pragma unroll
        for (int i = 0; i < 4; ++i)
            if (ob + i < NN) hs[ob + i] = vmax[i] / 255.f;
    }
    #pragma unroll
    for (int cc = 0; cc < 16; ++cc) {
        #pragma unroll
        for (int i = 0; i < 4; ++i) {
            if (ob + i < NN)
                hq[(size_t)(ob + i) * 256 + cc * 16 + lm] =
                    (unsigned char)(int)rintf(acc[cc][i] * invq[i]);
        }
    }
}

// ---------------- layer 1: u8 gather + dual MFMA -> h1 bf16 ----------------
__global__ __launch_bounds__(256, 4) void k_layer1(
    const unsigned char* __restrict__ hq, const float* __restrict__ hs,
    const ushort* __restrict__ Wl, const ushort* __restrict__ Wr,   // frag-major
    const float* __restrict__ bias, const float* __restrict__ invd,
    const int* __restrict__ rowptr, const int* __restrict__ colidx,
    ushort* __restrict__ hout)
{
    __shared__ ushort aggS[64 * 256];   // 32KB
    __shared__ int cidxS[2048];         // 8KB
    char* aggSb = (char*)aggS;
    const int t  = threadIdx.x;
    const int r0 = blockIdx.x * 64;
    const int l = t & 63;

    const int ebase = rowptr[r0];
    const int rend  = (r0 + 64 < NN) ? (r0 + 64) : NN;
    const int etot  = rowptr[rend] - ebase;
    const bool inlds = (etot <= 2048);
    if (inlds) {
        for (int i = t; i < etot; i += 256) cidxS[i] = colidx[ebase + i];
    }
    __syncthreads();

    // ---- phase 1: 16 lanes per row, 4 rows serial per group ----
    {
        const int gid = t >> 4, li = t & 15;
        const int base = l & ~15;
        for (int rr = gid; rr < 64; rr += 16) {
            const int r = r0 + rr;
            float acc[16];
            #pragma unroll
            for (int k = 0; k < 16; ++k) acc[k] = 0.f;
            if (r < NN) {
                const int beg = rowptr[r], end = rowptr[r + 1];
                for (int e = beg; e < end; e += 8) {
                    const int myi = e + (li & 7);
                    int se = -1;
                    if (myi < end) se = inlds ? cidxS[myi - ebase] : colidx[myi];
                    float mysc = (se >= 0) ? hs[se] : 0.f;
                    int   sj[8];
                    float sc[8];
                    uint4 u[8];
                    #pragma unroll
                    for (int j = 0; j < 8; ++j) sj[j] = __shfl(se, base + j);
                    #pragma unroll
                    for (int j = 0; j < 8; ++j) sc[j] = __shfl(mysc, base + j);
                    #pragma unroll
                    for (int j = 0; j < 8; ++j) {
                        u[j] = (sj[j] >= 0)
                            ? *(const uint4*)(hq + (((unsigned)sj[j]) << 8) + (li << 4))
                            : make_uint4(0u, 0u, 0u, 0u);
                    }
                    #pragma unroll
                    for (int j = 0; j < 8; ++j) {
                        #pragma unroll
                        for (int wi = 0; wi < 4; ++wi) {
                            unsigned w = (&u[j].x)[wi];
                            acc[wi*4+0] = fmaf(sc[j], ubf(w, 0), acc[wi*4+0]);
                            acc[wi*4+1] = fmaf(sc[j], ubf(w, 1), acc[wi*4+1]);
                            acc[wi*4+2] = fmaf(sc[j], ubf(w, 2), acc[wi*4+2]);
                            acc[wi*4+3] = fmaf(sc[j], ubf(w, 3), acc[wi*4+3]);
                        }
                    }
                }
                const float iv = invd[r];
                #pragma unroll
                for (int k = 0; k < 16; ++k) acc[k] *= iv;
            }
            #pragma unroll
            for (int gg = 0; gg < 2; ++gg) {
                unsigned q0 = (unsigned)f2bf(acc[gg*8+0]) | ((unsigned)f2bf(acc[gg*8+1]) << 16);
                unsigned q1 = (unsigned)f2bf(acc[gg*8+2]) | ((unsigned)f2bf(acc[gg*8+3]) << 16);
                unsigned q2 = (unsigned)f2bf(acc[gg*8+4]) | ((unsigned)f2bf(acc[gg*8+5]) << 16);
                unsigned q3 = (unsigned)f2bf(acc[gg*8+6]) | ((unsigned)f2bf(acc[gg*8+7]) << 16);
                int g  = li * 2 + gg;
                int gs = g ^ (rr & 7);
                *(uint4*)(aggSb + (size_t)rr * 512 + (gs << 4)) = make_uint4(q0, q1, q2, q3);
            }
        }
    }
    __syncthreads();

    // ---- phase 2: frag-hoisted dual MFMA over HID in 16-col chunks ----
    const int w = t >> 6, lm = l & 15, lk = l >> 4;
    const int rr = w * 16 + lm;
    const int rg = r0 + rr;

    bf16x8 ax[8];
    {
        const float sr = (rg < NN) ? hs[rg] : 0.f;
        #pragma unroll
        for (int kk = 0; kk < 8; ++kk) {
            uint2 uq = (rg < NN)
                ? *(const uint2*)(hq + (((unsigned)rg) << 8) + kk * 32 + lk * 8)
                : make_uint2(0u, 0u);
            bf16x8 v;
            v[0] = (short)f2bf(sr * ubf(uq.x, 0));
            v[1] = (short)f2bf(sr * ubf(uq.x, 1));
            v[2] = (short)f2bf(sr * ubf(uq.x, 2));
            v[3] = (short)f2bf(sr * ubf(uq.x, 3));
            v[4] = (short)f2bf(sr * ubf(uq.y, 0));
            v[5] = (short)f2bf(sr * ubf(uq.y, 1));
            v[6] = (short)f2bf(sr * ubf(uq.y, 2));
            v[7] = (short)f2bf(sr * ubf(uq.y, 3));
            ax[kk] = v;
        }
    }
    bf16x8 agg_reg[8];
    #pragma unroll
    for (int kk = 0; kk < 8; ++kk) {
        int g  = kk * 4 + lk;
        int gs = g ^ (rr & 7);
        agg_reg[kk] = *(const bf16x8*)(aggSb + (size_t)rr * 512 + (gs << 4));
    }

    for (int cc = 0; cc < 16; ++cc) {
        const int c = cc * 16 + lm;
        f32x4 acc = {0.f, 0.f, 0.f, 0.f};
        #pragma unroll
        for (int kk = 0; kk < 8; ++kk) {
            const size_t wf = ((size_t)(cc * 8 + kk) * 64 + l) * 8;
            bf16x8 bl = *(const bf16x8*)(Wl + wf);
            bf16x8 br = *(const bf16x8*)(Wr + wf);
            acc = __builtin_amdgcn_mfma_f32_16x16x32_bf16(agg_reg[kk], bl, acc, 0, 0, 0);
            acc = __builtin_amdgcn_mfma_f32_16x16x32_bf16(ax[kk],      br, acc, 0, 0, 0);
        }
        const float bv = bias[c];
        #pragma unroll
        for (int i = 0; i < 4; ++i) {
            const int orow = r0 + w * 16 + lk * 4 + i;
            if (orow < NN) {
                float v = fmaxf(acc[i] + bv, 0.f);
                hout[(size_t)orow * HID + c] = f2bf(v);
            }
        }
    }
}

// ---------------- premul: qq = biased-u8(h1@Wlo^T)+sq, rbuf = h1@Wro^T+bo ----------------
__global__ __launch_bounds__(256, 4) void k_premul(
    const ushort* __restrict__ h1, const ushort* __restrict__ wlo,
    const ushort* __restrict__ wro, const float* __restrict__ bo,
    unsigned char* __restrict__ qq, float* __restrict__ sq, float* __restrict__ rbuf)
{
    const int t = threadIdx.x;
    const int r0 = blockIdx.x * 64;
    const int w = t >> 6, l = t & 63, lm = l & 15, lk = l >> 4;
    const int rr = w * 16 + lm;
    const int rg = r0 + rr;

    f32x4 aq[3], ar[3];
    #pragma unroll
    for (int cc = 0; cc < 3; ++cc) { aq[cc] = {0.f,0.f,0.f,0.f}; ar[cc] = {0.f,0.f,0.f,0.f}; }

    #pragma unroll
    for (int kk = 0; kk < 8; ++kk) {
        bf16x8 a = (rg < NN)
            ? *(const bf16x8*)(h1 + (size_t)rg * 256 + kk * 32 + lk * 8)
            : (bf16x8)(short)0;
        #pragma unroll
        for (int cc = 0; cc < 3; ++cc) {
            const size_t wf = ((size_t)(cc * 8 + kk) * 64 + l) * 8;
            bf16x8 bl = *(const bf16x8*)(wlo + wf);
            bf16x8 br = *(const bf16x8*)(wro + wf);
            aq[cc] = __builtin_amdgcn_mfma_f32_16x16x32_bf16(a, bl, aq[cc], 0, 0, 0);
            ar[cc] = __builtin_amdgcn_mfma_f32_16x16x32_bf16(a, br, ar[cc], 0, 0, 0);
        }
    }

    #pragma unroll
    for (int i = 0; i < 4; ++i) {
        const int orow = r0 + w * 16 + lk * 4 + i;
        if (orow >= NN) continue;
        float m = 0.f;
        #pragma unroll
        for (int cc = 0; cc < 3; ++cc) {
            const int c = cc * 16 + lm;
            if (c < OUTC) m = fmaxf(m, fabsf(aq[cc][i]));
        }
        m = fmaxf(m, __shfl_xor(m, 1));
        m = fmaxf(m, __shfl_xor(m, 2));
        m = fmaxf(m, __shfl_xor(m, 4));
        m = fmaxf(m, __shfl_xor(m, 8));
        const float inv = (m > 0.f) ? 127.f / m : 0.f;
        #pragma unroll
        for (int cc = 0; cc < 3; ++cc) {
            const int c = cc * 16 + lm;
            int code = (c < OUTC) ? (int)rintf(aq[cc][i] * inv) : 0;
            qq[(size_t)orow * 64 + c] = (unsigned char)(code + 128);
            rbuf[(size_t)orow * 64 + c] = (c < OUTC) ? (ar[cc][i] + bo[c]) : 0.f;
        }
        qq[(size_t)orow * 64 + 48 + lm] = (unsigned char)128;
        rbuf[(size_t)orow * 64 + 48 + lm] = 0.f;
        if (lm == 0) sq[orow] = m / 127.f;
    }
}

// ---------------- final: out = log_softmax(mean_agg(q) + r), 4 lanes per row ----------------
__global__ __launch_bounds__(256) void k_final(
    const unsigned char* __restrict__ qq, const float* __restrict__ sq,
    const float* __restrict__ rbuf, const float* __restrict__ invd,
    const int* __restrict__ rowptr, const int* __restrict__ colidx,
    float* __restrict__ out)
{
    __shared__ int cidxS[2048];
    const int t = threadIdx.x;
    const int g = t >> 2, li = t & 3;
    const int r0 = blockIdx.x * 64;
    const int row = r0 + g;
    const int l = t & 63;
    const int base = l & ~3;

    const int ebase = rowptr[r0];
    const int rend  = (r0 + 64 < NN) ? (r0 + 64) : NN;
    const int etot  = rowptr[rend] - ebase;
    const bool inlds = (etot <= 2048);
    if (inlds) {
        for (int i = t; i < etot; i += 256) cidxS[i] = colidx[ebase + i];
    }
    __syncthreads();
    if (row >= NN) return;

    float acc[16];
    #pragma unroll
    for (int k = 0; k < 16; ++k) acc[k] = 0.f;
    float sum_sc = 0.f;

    const int beg = rowptr[row], end = rowptr[row + 1];
    for (int e = beg; e < end; e += 8) {
        const int m0 = e + li, m1 = e + 4 + li;
        int se0 = -1, se1 = -1;
        if (m0 < end) se0 = inlds ? cidxS[m0 - ebase] : colidx[m0];
        if (m1 < end) se1 = inlds ? cidxS[m1 - ebase] : colidx[m1];
        float ms0 = (se0 >= 0) ? sq[se0] : 0.f;
        float ms1 = (se1 >= 0) ? sq[se1] : 0.f;
        int   sj[8];
        float sc[8];
        uint4 u[8];
        #pragma unroll
        for (int j = 0; j < 4; ++j) { sj[j] = __shfl(se0, base + j); sc[j] = __shfl(ms0, base + j); }
        #pragma unroll
        for (int j = 4; j < 8; ++j) { sj[j] = __shfl(se1, base + j - 4); sc[j] = __shfl(ms1, base + j - 4); }
        #pragma unroll
        for (int j = 0; j < 8; ++j) {
            u[j] = (sj[j] >= 0)
                ? *(const uint4*)(qq + (((unsigned)sj[j]) << 6) + (li << 4))
                : make_uint4(0u, 0u, 0u, 0u);
        }
        #pragma unroll
        for (int j = 0; j < 8; ++j) {
            #pragma unroll
            for (int wi = 0; wi < 4; ++wi) {
                unsigned w = (&u[j].x)[wi];
                acc[wi*4+0] = fmaf(sc[j], ubf(w, 0), acc[wi*4+0]);
                acc[wi*4+1] = fmaf(sc[j], ubf(w, 1), acc[wi*4+1]);
                acc[wi*4+2] = fmaf(sc[j], ubf(w, 2), acc[wi*4+2]);
                acc[wi*4+3] = fmaf(sc[j], ubf(w, 3), acc[wi*4+3]);
            }
            sum_sc += sc[j];
        }
    }

    const float iv = invd[row];
    const float4* rp = (const float4*)(rbuf + (size_t)row * 64 + li * 16);
    float v[16];
    #pragma unroll
    for (int ch = 0; ch < 4; ++ch) {
        float4 rv = rp[ch];
        v[ch*4+0] = (acc[ch*4+0] - 128.f * sum_sc) * iv + rv.x;
        v[ch*4+1] = (acc[ch*4+1] - 128.f * sum_sc) * iv + rv.y;
        v[ch*4+2] = (acc[ch*4+2] - 128.f * sum_sc) * iv + rv.z;
        v[ch*4+3] = (acc[ch*4+3] - 128.f * sum_sc) * iv + rv.w;
    }
    #pragma unroll
    for (int k = 0; k < 16; ++k)
        if (li * 16 + k >= OUTC) v[k] = -INFINITY;

    float m = v[0];
    #pragma unroll
    for (int k = 1; k < 16; ++k) m = fmaxf(m, v[k]);
    m = fmaxf(m, __shfl_xor(m, 1));
    m = fmaxf(m, __shfl_xor(m, 2));

    float s = 0.f;
    #pragma unroll
    for (int k = 0; k < 16; ++k)
        if (li * 16 + k < OUTC) s += __expf(v[k] - m);
    s += __shfl_xor(s, 1);
    s += __shfl_xor(s, 2);
    const float ls = __logf(s);

    #pragma unroll
    for (int ch = 0; ch < 4; ++ch) {
        const int c = li * 16 + ch * 4;
        if (c < OUTC) {
            float4 o;
            o.x = v[ch*4+0] - m - ls;
            o.y = v[ch*4+1] - m - ls;
            o.z = v[ch*4+2] - m - ls;
            o.w = v[ch*4+3] - m - ls;
            *(float4*)(out + (size_t)row * OUTC + c) = o;
        }
    }
}

extern "C" void kernel_launch(void* const* d_in, const int* in_sizes, int n_in,
                              void* d_out, int out_size, void* d_ws, size_t ws_size,
                              hipStream_t stream) {
    const float* x   = (const float*)d_in[0];
    const int*   ei  = (const int*)d_in[1];
    const int*   src = ei;
    const int*   dst = ei + NE;
    const float* Wl0 = (const float*)d_in[2];
    const float* Wr0 = (const float*)d_in[3];
    const float* b0  = (const float*)d_in[4];
    const float* Wl1 = (const float*)d_in[5];
    const float* Wr1 = (const float*)d_in[6];
    const float* b1  = (const float*)d_in[7];
    const float* Wlo = (const float*)d_in[8];
    const float* Wro = (const float*)d_in[9];
    const float* bo  = (const float*)d_in[10];
    float* out = (float*)d_out;

    char* ws = (char*)d_ws;
    const size_t MB = 1 << 20;
    float*         invd   = (float*)(ws + 0);
    int*           rowptr = (int*)(ws + MB / 2);
    int*           cnt    = (int*)(ws + MB);
    int*           fillp  = (int*)(ws + MB + MB / 2);
    int*           bsum   = (int*)(ws + 2 * MB);
    int*           boff   = (int*)(ws + 2 * MB + MB / 4);
    float*         sx     = (float*)(ws + 2 * MB + MB / 2);
    float*         s0     = (float*)(ws + 3 * MB);
    float*         sq     = (float*)(ws + 3 * MB + MB / 2);
    ushort*        Wb     = (ushort*)(ws + 4 * MB);            // 442KB frag-major
    int*           colidx = (int*)(ws + 4 * MB + MB / 2);      // 6.4MB -> ends ~10.9
    unsigned char* xq8    = (unsigned char*)(ws + 11 * MB);    // [N,128] u8 = 12.8MB (11..23.8)
    unsigned char* qq     = (unsigned char*)(ws + 11 * MB);    // aliases xq8 (dead after layer0)
    unsigned char* h0q    = (unsigned char*)(ws + 24 * MB);    // [N,256] u8 = 25.6MB (24..49.6)
    float*         rbuf   = (float*)(ws + 24 * MB);            // aliases h0q (h0q dead after layer1)
    ushort*        h1     = (ushort*)(ws + 50 * MB);           // [N,256] bf16 = 51.2MB (50..101.2)

    ushort* wl0 = Wb;                 // 16*4*64*8  = 32768
    ushort* wr0 = Wb + 32768;
    ushort* wl1 = Wb + 65536;         // 16*8*64*8  = 65536
    ushort* wr1 = Wb + 131072;
    ushort* wlo = Wb + 196608;        // 3*8*64*8   = 12288 (48-row zero-padded)
    ushort* wro = Wb + 208896;

    // CSR build
    hipMemsetAsync(cnt, 0, NN * sizeof(int), stream);
    k_count<<<(NE + 255) / 256, 256, 0, stream>>>(dst, cnt);
    const int NB = (NN + 255) / 256;  // 391
    k_blocksum<<<NB, 256, 0, stream>>>(cnt, bsum);
    k_scanblock<<<1, 512, 0, stream>>>(bsum, boff, NB);
    k_rowptr<<<NB, 256, 0, stream>>>(cnt, boff, rowptr, fillp, invd);
    k_fill<<<(NE + 255) / 256, 256, 0, stream>>>(src, dst, fillp, colidx);

    // weights -> fragment-major bf16; x -> biased u8
    k_cvtfrag<<<16, 256, 0, stream>>>(Wl0, wl0, 256, 128, 4096);
    k_cvtfrag<<<16, 256, 0, stream>>>(Wr0, wr0, 256, 128, 4096);
    k_cvtfrag<<<32, 256, 0, stream>>>(Wl1, wl1, 256, 256, 8192);
    k_cvtfrag<<<32, 256, 0, stream>>>(Wr1, wr1, 256, 256, 8192);
    k_cvtfrag<<<6,  256, 0, stream>>>(Wlo, wlo, 40, 256, 1536);
    k_cvtfrag<<<6,  256, 0, stream>>>(Wro, wro, 40, 256, 1536);
    k_quant_x8<<<(NN + 15) / 16, 256, 0, stream>>>(x, xq8, sx);

    const int GB = (NN + 63) / 64;  // 1563
    // layer 0 (fused u8-quant output): gather biased-u8 x, self fp32 x -> h0q u8 + s0
    k_layer0<<<GB, 256, 0, stream>>>(xq8, sx, x, wl0, wr0, b0, invd, rowptr, colidx, h0q, s0);
    // layer 1: gather u8 h0, self u8 h0 -> h1 bf16
    k_layer1<<<GB, 256, 0, stream>>>(h0q, s0, wl1, wr1, b1, invd, rowptr, colidx, h1);
    // premul: h1 -> qq (biased u8), sq, rbuf
    k_premul<<<GB, 256, 0, stream>>>(h1, wlo, wro, bo, qq, sq, rbuf);
    // final: 1-line-per-edge gather + log_softmax
    k_final<<<GB, 256, 0, stream>>>(qq, sq, rbuf, invd, rowptr, colidx, out);
}